// Round 3
// baseline (898.443 us; speedup 1.0000x reference)
//
#include <hip/hip_runtime.h>
#include <hip/hip_cooperative_groups.h>
#include <math.h>

#pragma clang fp contract(off)

namespace cg = cooperative_groups;

#define BN 4
#define SX 512
#define SY 512
#define NPIX (BN * SX * SY)
#define MU 5
#define MB (1024 * 1024)
#define NBLOCKS 4096   // (SY/256) * SX * BN  (fallback partial count)

#define VTY 32
#define VTX 16

struct DogW  { float g[7];  float tw; };
struct FdogW { float g[10]; float tw; };
struct AllW  { DogW dw; FdogW fw; };

// tanh via expm1 identity: tanh(d) = expm1(2|d|) / (expm1(2|d|) + 2), odd.
__device__ __forceinline__ float fast_tanh_f32(float dF) {
    double d = (double)dF;
    double y = fabs(d);
    double t = expm1(2.0 * y);
    double r = t / (t + 2.0);
    if (y > 350.0) r = 1.0;
    return (float)copysign(r, d);
}

__device__ __forceinline__ float img_at(const float* __restrict__ img, int b, int x, int y) {
    if (x < 0 || x >= SX || y < 0 || y >= SY) return 0.0f;
    return img[(size_t)b * SX * SY + (size_t)x * SY + y];
}

// ---------------------------------------------------------------------------
// Mega cooperative kernel: sobel -> (implicit reduce) -> tanh -> 3x(V,H[+dog])
// -> fdog, with grid.sync() between stages. Arithmetic identical to the
// split kernels -> bit-exact. Grid-stride over each stage's tile space.
// ---------------------------------------------------------------------------
struct VLds { float2 sT[VTX + 2 * MU][VTY]; float sTV[5][VTX + MU][VTY]; }; // 20096 B
struct HLds { float2 sT[SY]; float sTH[5][SY]; };                           // 14336 B
union MegaLds { VLds v; HLds h; float red[4]; };

__global__ __launch_bounds__(256) void k_mega(
    const float* __restrict__ img, float* __restrict__ mag,
    float2* __restrict__ tA, float2* __restrict__ tB,
    float* __restrict__ TV, float* __restrict__ TH,
    float* __restrict__ partial, int* __restrict__ out, AllW w)
{
#pragma clang fp contract(off)
    cg::grid_group grid = cg::this_grid();
    __shared__ MegaLds L;
    const int tid  = threadIdx.x;
    const int bid  = blockIdx.x;
    const int G    = gridDim.x;
    const int lane = tid & 63;
    const int wid  = tid >> 6;

    // ---- Stage 1: Sobel + per-block running max ----
    float wm = 0.0f;
    for (int t = bid; t < 4096; t += G) {
        int bx = t & 1;
        int xi = (t >> 1) & 511;
        int b  = t >> 10;
        int yi = bx * 256 + tid;

        float v00 = img_at(img, b, xi - 1, yi - 1);
        float v01 = img_at(img, b, xi - 1, yi    );
        float v02 = img_at(img, b, xi - 1, yi + 1);
        float v10 = img_at(img, b, xi,     yi - 1);
        float v12 = img_at(img, b, xi,     yi + 1);
        float v20 = img_at(img, b, xi + 1, yi - 1);
        float v21 = img_at(img, b, xi + 1, yi    );
        float v22 = img_at(img, b, xi + 1, yi + 1);

        float s0 = (-1.0f * v00);
        s0 = s0 + (-2.0f * v01);
        s0 = s0 + (-1.0f * v02);
        s0 = s0 + ( 1.0f * v20);
        s0 = s0 + ( 2.0f * v21);
        s0 = s0 + ( 1.0f * v22);
        float s1 = (-1.0f * v00);
        s1 = s1 + ( 1.0f * v02);
        s1 = s1 + (-2.0f * v10);
        s1 = s1 + ( 2.0f * v12);
        s1 = s1 + (-1.0f * v20);
        s1 = s1 + ( 1.0f * v22);

        float m = sqrtf((s0 * s0) + (s1 * s1));
        size_t idx = (size_t)b * SX * SY + (size_t)xi * SY + yi;
        mag[idx] = m;

        float tx = -s1, ty = s0;
        float n = sqrtf((tx * tx) + (ty * ty));
        float d = (n == 0.0f) ? 1.0f : n;
        tA[idx] = make_float2(tx / d, ty / d);

        wm = fmaxf(wm, m);
    }
    for (int off = 32; off > 0; off >>= 1) wm = fmaxf(wm, __shfl_down(wm, off, 64));
    if (lane == 0) L.red[wid] = wm;
    __syncthreads();
    if (tid == 0)
        partial[bid] = fmaxf(fmaxf(L.red[0], L.red[1]), fmaxf(L.red[2], L.red[3]));
    grid.sync();

    // ---- Stage 2: every block redundantly reduces partials -> mx (register) ----
    float m2 = 0.0f;
    for (int i = tid; i < G; i += 256) m2 = fmaxf(m2, partial[i]);
    for (int off = 32; off > 0; off >>= 1) m2 = fmaxf(m2, __shfl_down(m2, off, 64));
    __syncthreads();
    if (lane == 0) L.red[wid] = m2;
    __syncthreads();
    const float mx = fmaxf(fmaxf(L.red[0], L.red[1]), fmaxf(L.red[2], L.red[3]));

    // ---- Stage 3: tanh difference fields (normalization fused) ----
    for (int t = bid; t < 4096; t += G) {
        int bx = t & 1;
        int xi = (t >> 1) & 511;
        int b  = t >> 10;
        int yi = bx * 256 + tid;
        size_t base = (size_t)b * SX * SY;
        size_t idx  = base + (size_t)xi * SY + yi;
        float cm = mag[idx] / mx;
#pragma unroll
        for (int k = 1; k <= 5; ++k) {
            if (xi + k < SX) {
                float nm = mag[idx + (size_t)k * SY] / mx;
                TV[(size_t)(k - 1) * NPIX + idx] = fast_tanh_f32(nm - cm);
            }
        }
#pragma unroll
        for (int k = 1; k <= 5; ++k) {
            if (yi + k < SY) {
                float nm = mag[idx + k] / mx;
                TH[(size_t)(k - 1) * NPIX + idx] = fast_tanh_f32(nm - cm);
            }
        }
    }
    grid.sync();

    // ---- Stage 4: 3 ETF iterations (V then H; DoG fused into last H) ----
    float2* src = tA;
    float2* dst = tB;
    for (int it = 0; it < 3; ++it) {
        // V-pass: 2048 tiles of 32(y) x 16(x)
        for (int t = bid; t < 2048; t += G) {
            __syncthreads();   // LDS reuse guard across tiles
            int y0 = (t & 15) * VTY;
            int x0 = ((t >> 4) & 31) * VTX;
            int b  = t >> 9;
            size_t base = (size_t)b * SX * SY;

            for (int i = tid; i < (VTX + 2 * MU) * (VTY / 4) * 2; i += 256) {
                int r = i >> 4;
                int c = i & 15;
                int gx = x0 - MU + r;
                if (gx >= 0 && gx < SX)
                    ((float4*)&L.v.sT[r][0])[c] =
                        ((const float4*)(src + base + (size_t)gx * SY + y0))[c];
            }
            for (int i = tid; i < 5 * (VTX + MU) * (VTY / 4); i += 256) {
                int j   = i / ((VTX + MU) * (VTY / 4));
                int rem = i - j * ((VTX + MU) * (VTY / 4));
                int r   = rem >> 3;
                int c   = rem & 7;
                int gx  = x0 - MU + r;
                if (gx >= 0 && gx < SX)
                    ((float4*)&L.v.sTV[j][r][0])[c] =
                        ((const float4*)(TV + (size_t)j * NPIX + base + (size_t)gx * SY + y0))[c];
            }
            __syncthreads();

            int ty  = tid & 31;
            int txw = tid >> 5;
            int yi  = y0 + ty;
#pragma unroll
            for (int sub = 0; sub < 2; ++sub) {
                int tx = txw + (sub << 3);
                int xi = x0 + tx;
                size_t idx = base + (size_t)xi * SY + yi;

                float2 ct = L.v.sT[tx + MU][ty];
                float sx = 0.0f, sy = 0.0f;
#pragma unroll
                for (int k = -MU; k <= MU; ++k) {
                    int nx = xi + k;
                    if (nx < 0 || nx >= SX) continue;
                    float2 nt = L.v.sT[tx + MU + k][ty];
                    float th;
                    if (k > 0)      th =  L.v.sTV[k - 1][tx + MU][ty];
                    else if (k < 0) th = -L.v.sTV[-k - 1][tx + MU + k][ty];
                    else            th =  0.0f;
                    float dot = (ct.x * nt.x) + (ct.y * nt.y);
                    float ww  = ((th + 1.0f) * dot) * 0.5f;
                    sx = sx + (nt.x * ww);
                    sy = sy + (nt.y * ww);
                }
                float n = sqrtf((sx * sx) + (sy * sy));
                float d = (n == 0.0f) ? 1.0f : n;
                dst[idx] = make_float2(sx / d, sy / d);
            }
        }
        grid.sync();
        { float2* tswp = src; src = dst; dst = tswp; }

        // H-pass: 2048 tiles (one image row each); DoG fused on last iter
        int do_dog = (it == 2);
        for (int t = bid; t < 2048; t += G) {
            __syncthreads();   // LDS reuse guard
            int xi = t & 511;
            int b  = t >> 9;
            size_t base    = (size_t)b * SX * SY;
            size_t rowbase = base + (size_t)xi * SY;

            ((float4*)L.h.sT)[tid] = ((const float4*)(src + rowbase))[tid];
            for (int i = tid; i < 5 * (SY / 4); i += 256) {
                int j = i >> 7;
                int c = i & 127;
                ((float4*)&L.h.sTH[0][0])[i] =
                    ((const float4*)(TH + (size_t)j * NPIX + rowbase))[c];
            }
            __syncthreads();

#pragma unroll
            for (int half = 0; half < 2; ++half) {
                int yi = tid + half * 256;
                float2 ct = L.h.sT[yi];
                float sx = 0.0f, sy = 0.0f;
#pragma unroll
                for (int k = -MU; k <= MU; ++k) {
                    int ny = yi + k;
                    if (ny < 0 || ny >= SY) continue;
                    float2 nt = L.h.sT[ny];
                    float th;
                    if (k > 0)      th =  L.h.sTH[k - 1][yi];
                    else if (k < 0) th = -L.h.sTH[-k - 1][ny];
                    else            th =  0.0f;
                    float dot = (ct.x * nt.x) + (ct.y * nt.y);
                    float ww  = ((th + 1.0f) * dot) * 0.5f;
                    sx = sx + (nt.x * ww);
                    sy = sy + (nt.y * ww);
                }
                float n = sqrtf((sx * sx) + (sy * sy));
                float d = (n == 0.0f) ? 1.0f : n;
                float ex = sx / d;
                float ey = sy / d;
                dst[rowbase + yi] = make_float2(ex, ey);

                if (do_dog) {
                    float perx = -ey;
                    float pery =  ex;
                    float xf = (float)xi, yf = (float)yi;
                    float acc = 0.0f;
#pragma unroll
                    for (int tt = -3; tt <= 3; ++tt) {
                        float tf  = (float)tt;
                        float ptx = xf + (perx * tf);
                        float pty = yf + (pery * tf);
                        int px = (int)rintf(fminf(fmaxf(ptx, 0.0f), (float)(SX - 1)));
                        int py = (int)rintf(fminf(fmaxf(pty, 0.0f), (float)(SY - 1)));
                        float il = img[base + (size_t)px * SY + py];
                        acc = acc + (il * w.dw.g[tt + 3]);
                    }
                    mag[rowbase + yi] = acc / w.dw.tw;   // mag reused as dog
                }
            }
        }
        grid.sync();
        { float2* tswp = src; src = dst; dst = tswp; }
    }

    // ---- Stage 5: FDoG (src = final ETF, mag = dog) ----
    for (int t = bid; t < 4096; t += G) {
        int bx = t & 1;
        int xi = (t >> 1) & 511;
        int b  = t >> 10;
        int yi = bx * 256 + tid;
        size_t base = (size_t)b * SX * SY;
        size_t idx  = base + (size_t)xi * SY + yi;

        float d1[9];
        float d2[10];
        float2 e0 = src[idx];
        float2 e1 = e0, e2 = e0;
        int p1x = xi, p1y = yi;
        int p2x = xi, p2y = yi;
        d2[0] = mag[idx];

#pragma unroll
        for (int s = 1; s <= 9; ++s) {
            float fx1 = (float)p1x + (e1.x * -1.0f);
            float fy1 = (float)p1y + (e1.y * -1.0f);
            p1x = (int)rintf(fminf(fmaxf(fx1, 0.0f), (float)(SX - 1)));
            p1y = (int)rintf(fminf(fmaxf(fy1, 0.0f), (float)(SY - 1)));
            size_t i1 = base + (size_t)p1x * SY + p1y;
            float fx2 = (float)p2x + (e2.x * 1.0f);
            float fy2 = (float)p2y + (e2.y * 1.0f);
            p2x = (int)rintf(fminf(fmaxf(fx2, 0.0f), (float)(SX - 1)));
            p2y = (int)rintf(fminf(fmaxf(fy2, 0.0f), (float)(SY - 1)));
            size_t i2 = base + (size_t)p2x * SY + p2y;

            d1[s - 1] = mag[i1];
            d2[s]     = mag[i2];
            if (s < 9) {
                e1 = src[i1];
                e2 = src[i2];
            }
        }

        float acc = 0.0f;
#pragma unroll
        for (int s = 1; s <= 9; ++s) acc = acc + (d1[s - 1] * w.fw.g[s]);
        acc = acc + (d2[0] * w.fw.g[0]);
#pragma unroll
        for (int s = 1; s <= 9; ++s) acc = acc + (d2[s] * w.fw.g[s]);

        float fv = acc / w.fw.tw;
        float th = 1.0f + fast_tanh_f32(fv);
        out[idx] = ((fv < 0.0f) && (th < 0.7f)) ? 0 : 1;
    }
}

// ---------------------------------------------------------------------------
// Fallback split kernels (identical to round-2 verified versions)
// ---------------------------------------------------------------------------
__global__ void k_sobel(const float* __restrict__ img, float* __restrict__ mag,
                        float2* __restrict__ tang, float* __restrict__ partial) {
#pragma clang fp contract(off)
    int yi = blockIdx.x * blockDim.x + threadIdx.x;
    int xi = blockIdx.y;
    int b  = blockIdx.z;

    float v00 = img_at(img, b, xi - 1, yi - 1);
    float v01 = img_at(img, b, xi - 1, yi    );
    float v02 = img_at(img, b, xi - 1, yi + 1);
    float v10 = img_at(img, b, xi,     yi - 1);
    float v12 = img_at(img, b, xi,     yi + 1);
    float v20 = img_at(img, b, xi + 1, yi - 1);
    float v21 = img_at(img, b, xi + 1, yi    );
    float v22 = img_at(img, b, xi + 1, yi + 1);

    float s0 = (-1.0f * v00);
    s0 = s0 + (-2.0f * v01);
    s0 = s0 + (-1.0f * v02);
    s0 = s0 + ( 1.0f * v20);
    s0 = s0 + ( 2.0f * v21);
    s0 = s0 + ( 1.0f * v22);
    float s1 = (-1.0f * v00);
    s1 = s1 + ( 1.0f * v02);
    s1 = s1 + (-2.0f * v10);
    s1 = s1 + ( 2.0f * v12);
    s1 = s1 + (-1.0f * v20);
    s1 = s1 + ( 1.0f * v22);

    float m = sqrtf((s0 * s0) + (s1 * s1));
    size_t idx = (size_t)b * SX * SY + (size_t)xi * SY + yi;
    mag[idx] = m;

    float tx = -s1, ty = s0;
    float n = sqrtf((tx * tx) + (ty * ty));
    float d = (n == 0.0f) ? 1.0f : n;
    tang[idx] = make_float2(tx / d, ty / d);

    float wm = m;
    for (int off = 32; off > 0; off >>= 1) wm = fmaxf(wm, __shfl_down(wm, off, 64));
    __shared__ float red[4];
    int lane = threadIdx.x & 63;
    int wid  = threadIdx.x >> 6;
    if (lane == 0) red[wid] = wm;
    __syncthreads();
    if (threadIdx.x == 0) {
        float bm = fmaxf(fmaxf(red[0], red[1]), fmaxf(red[2], red[3]));
        int bid = blockIdx.x + gridDim.x * (blockIdx.y + gridDim.y * blockIdx.z);
        partial[bid] = bm;
    }
}

__global__ void k_reduce(const float* __restrict__ partial, unsigned int* __restrict__ maxbits) {
    float m = 0.0f;
    for (int i = threadIdx.x; i < NBLOCKS; i += 256) m = fmaxf(m, partial[i]);
    for (int off = 32; off > 0; off >>= 1) m = fmaxf(m, __shfl_down(m, off, 64));
    __shared__ float red[4];
    int lane = threadIdx.x & 63;
    int wid  = threadIdx.x >> 6;
    if (lane == 0) red[wid] = m;
    __syncthreads();
    if (threadIdx.x == 0) {
        float bm = fmaxf(fmaxf(red[0], red[1]), fmaxf(red[2], red[3]));
        *maxbits = __float_as_uint(bm);
    }
}

__global__ void k_norm(float* __restrict__ mag, const unsigned int* __restrict__ maxbits) {
    int i = blockIdx.x * blockDim.x + threadIdx.x;
    float mx = __uint_as_float(*maxbits);
    mag[i] = mag[i] / mx;
}

__global__ void k_etf(const float2* __restrict__ tsrc, float2* __restrict__ tdst,
                      const float* __restrict__ mag, int vert) {
#pragma clang fp contract(off)
    int yi = blockIdx.x * blockDim.x + threadIdx.x;
    int xi = blockIdx.y;
    int b  = blockIdx.z;
    size_t base = (size_t)b * SX * SY;
    size_t idx  = base + (size_t)xi * SY + yi;

    float  cm = mag[idx];
    float2 ct = tsrc[idx];

    float sx = 0.0f, sy = 0.0f;
    for (int k = -MU; k <= MU; ++k) {
        int nx = xi + (vert ? k : 0);
        int ny = yi + (vert ? 0 : k);
        if (nx < 0 || nx >= SX || ny < 0 || ny >= SY) continue;
        size_t nidx = base + (size_t)nx * SY + ny;
        float  nm = mag[nidx];
        float2 nt = tsrc[nidx];
        float dot = (ct.x * nt.x) + (ct.y * nt.y);
        float th  = (float)tanh((double)(nm - cm));
        float w   = ((th + 1.0f) * dot) * 0.5f;
        sx = sx + (nt.x * w);
        sy = sy + (nt.y * w);
    }
    float n = sqrtf((sx * sx) + (sy * sy));
    float d = (n == 0.0f) ? 1.0f : n;
    tdst[idx] = make_float2(sx / d, sy / d);
}

__global__ void k_dog(const float* __restrict__ img, const float2* __restrict__ etf,
                      float* __restrict__ dog, DogW w) {
#pragma clang fp contract(off)
    int yi = blockIdx.x * blockDim.x + threadIdx.x;
    int xi = blockIdx.y;
    int b  = blockIdx.z;
    size_t base = (size_t)b * SX * SY;
    size_t idx  = base + (size_t)xi * SY + yi;

    float2 e = etf[idx];
    float perx = -e.y;
    float pery =  e.x;
    float xf = (float)xi, yf = (float)yi;

    float acc = 0.0f;
#pragma unroll
    for (int t = -3; t <= 3; ++t) {
        float tf  = (float)t;
        float ptx = xf + (perx * tf);
        float pty = yf + (pery * tf);
        int px = (int)rintf(fminf(fmaxf(ptx, 0.0f), (float)(SX - 1)));
        int py = (int)rintf(fminf(fmaxf(pty, 0.0f), (float)(SY - 1)));
        float il = img[base + (size_t)px * SY + py];
        acc = acc + (il * w.g[t + 3]);
    }
    dog[idx] = acc / w.tw;
}

__global__ void k_fdog(const float* __restrict__ dog, const float2* __restrict__ etf,
                       int* __restrict__ out, FdogW w) {
#pragma clang fp contract(off)
    int yi = blockIdx.x * blockDim.x + threadIdx.x;
    int xi = blockIdx.y;
    int b  = blockIdx.z;
    size_t base = (size_t)b * SX * SY;
    size_t idx  = base + (size_t)xi * SY + yi;

    float d1[9];
    float d2[10];
    float2 e0 = etf[idx];
    float2 e1 = e0, e2 = e0;
    int p1x = xi, p1y = yi;
    int p2x = xi, p2y = yi;
    d2[0] = dog[idx];

#pragma unroll
    for (int s = 1; s <= 9; ++s) {
        float fx1 = (float)p1x + (e1.x * -1.0f);
        float fy1 = (float)p1y + (e1.y * -1.0f);
        p1x = (int)rintf(fminf(fmaxf(fx1, 0.0f), (float)(SX - 1)));
        p1y = (int)rintf(fminf(fmaxf(fy1, 0.0f), (float)(SY - 1)));
        size_t i1 = base + (size_t)p1x * SY + p1y;
        float fx2 = (float)p2x + (e2.x * 1.0f);
        float fy2 = (float)p2y + (e2.y * 1.0f);
        p2x = (int)rintf(fminf(fmaxf(fx2, 0.0f), (float)(SX - 1)));
        p2y = (int)rintf(fminf(fmaxf(fy2, 0.0f), (float)(SY - 1)));
        size_t i2 = base + (size_t)p2x * SY + p2y;

        d1[s - 1] = dog[i1];
        d2[s]     = dog[i2];
        if (s < 9) {
            e1 = etf[i1];
            e2 = etf[i2];
        }
    }

    float acc = 0.0f;
#pragma unroll
    for (int s = 1; s <= 9; ++s) acc = acc + (d1[s - 1] * w.g[s]);
    acc = acc + (d2[0] * w.g[0]);
#pragma unroll
    for (int s = 1; s <= 9; ++s) acc = acc + (d2[s] * w.g[s]);

    float fv = acc / w.tw;
    float th = 1.0f + fast_tanh_f32(fv);
    out[idx] = ((fv < 0.0f) && (th < 0.7f)) ? 0 : 1;
}

static double gpdf(double v, double sig) {
    return exp(-(v * v) / (2.0 * sig * sig)) / (sqrt(2.0 * M_PI) * sig);
}

// Compute (once) the cooperative grid size: occupancy-limited co-resident blocks.
static int mega_grid_size() {
    static int g = -2;
    if (g != -2) return g;
    int dev = 0;
    if (hipGetDevice(&dev) != hipSuccess) { g = -1; return g; }
    int coop = 0;
    if (hipDeviceGetAttribute(&coop, hipDeviceAttributeCooperativeLaunch, dev) != hipSuccess || !coop) {
        g = -1; return g;
    }
    hipDeviceProp_t p;
    if (hipGetDeviceProperties(&p, dev) != hipSuccess) { g = -1; return g; }
    int per = 0;
    if (hipOccupancyMaxActiveBlocksPerMultiprocessor(&per, (const void*)k_mega, 256, 0) != hipSuccess
        || per < 1) { g = -1; return g; }
    long long gg = (long long)per * (long long)p.multiProcessorCount;
    if (gg > 2048) gg = 2048;   // largest useful tile-space divisor
    g = (int)gg;
    return g;
}

extern "C" void kernel_launch(void* const* d_in, const int* in_sizes, int n_in,
                              void* d_out, int out_size, void* d_ws, size_t ws_size,
                              hipStream_t stream) {
    const float* img = (const float*)d_in[0];
    int* out = (int*)d_out;
    char* ws = (char*)d_ws;

    // Workspace layout (60 MB + 16 KB + 4 B):
    //   mag [0,4MB) (dog reuses) | tA [4,12) | tB [12,20)
    //   TV [20,40) | TH [40,60) | partial [60MB,+16KB) | maxbits [+4)
    const size_t need = (size_t)60 * MB + NBLOCKS * sizeof(float) + 4;
    bool fast = ws_size >= need;

    float*  mag = (float*)(ws);
    float2* tA  = (float2*)(ws + (size_t)4  * MB);
    float2* tB  = (float2*)(ws + (size_t)12 * MB);
    float*  TV  = (float*)(ws + (size_t)20 * MB);
    float*  TH  = (float*)(ws + (size_t)40 * MB);
    size_t  tail = fast ? (size_t)60 * MB : (size_t)20 * MB;
    float*        partial = (float*)(ws + tail);
    unsigned int* maxbits = (unsigned int*)(ws + tail + NBLOCKS * sizeof(float));

    dim3 blk(256, 1, 1);
    dim3 grd(SY / 256, SX, BN);
    dim3 hgrd(1, SX, BN);

    AllW aw;
    {
        double tw = 0.0;
        for (int t = -3; t <= 3; ++t) {
            double g = gpdf((double)t, 1.0) - 0.99 * gpdf((double)t, 1.6);
            aw.dw.g[t + 3] = (float)g;
            tw += g;
        }
        aw.dw.tw = (float)tw;
    }
    {
        for (int s = 0; s <= 9; ++s) aw.fw.g[s] = (float)gpdf((double)s, 3.0);
        double tw = 0.0;
        for (int s = 1; s <= 9; ++s) tw += gpdf((double)s, 3.0);
        for (int s = 0; s <= 9; ++s) tw += gpdf((double)s, 3.0);
        aw.fw.tw = (float)tw;
    }

    int G = fast ? mega_grid_size() : -1;
    if (G >= 256) {
        void* kargs[] = { (void*)&img, (void*)&mag, (void*)&tA, (void*)&tB,
                          (void*)&TV, (void*)&TH, (void*)&partial, (void*)&out,
                          (void*)&aw };
        hipError_t e = hipLaunchCooperativeKernel((const void*)k_mega,
                                                  dim3(G, 1, 1), blk, kargs, 0, stream);
        if (e == hipSuccess) return;
        // fall through to split path on failure
    }

    // ---------------- fallback: verified split-kernel path ----------------
    k_sobel<<<grd, blk, 0, stream>>>(img, mag, tA, partial);
    k_reduce<<<1, 256, 0, stream>>>(partial, maxbits);

    float2* src = tA;
    float2* dst = tB;
    k_norm<<<NPIX / 256, 256, 0, stream>>>(mag, maxbits);
    for (int it = 0; it < 3; ++it) {
        k_etf<<<grd, blk, 0, stream>>>(src, dst, mag, 1);
        { float2* t = src; src = dst; dst = t; }
        k_etf<<<grd, blk, 0, stream>>>(src, dst, mag, 0);
        { float2* t = src; src = dst; dst = t; }
    }
    float* dogbuf = (src == tA) ? (float*)tB : (float*)tA;
    k_dog<<<grd, blk, 0, stream>>>(img, src, dogbuf, aw.dw);
    k_fdog<<<grd, blk, 0, stream>>>(dogbuf, src, out, aw.fw);
}

// Round 4
// 213.447 us; speedup vs baseline: 4.2092x; 4.2092x over previous
//
#include <hip/hip_runtime.h>
#include <math.h>

#pragma clang fp contract(off)

#define BN 4
#define SX 512
#define SY 512
#define NPIX (BN * SX * SY)
#define MU 5
#define MB (1024 * 1024)
#define NBLOCKS 4096   // (SY/256) * SX * BN

struct DogW  { float g[7];  float tw; };
struct FdogW { float g[10]; float tw; };

// tanh via expm1 identity: tanh(d) = expm1(2|d|) / (expm1(2|d|) + 2), odd.
__device__ __forceinline__ float fast_tanh_f32(float dF) {
    double d = (double)dF;
    double y = fabs(d);
    double t = expm1(2.0 * y);
    double r = t / (t + 2.0);
    if (y > 350.0) r = 1.0;
    return (float)copysign(r, d);
}

__device__ __forceinline__ float img_at(const float* __restrict__ img, int b, int x, int y) {
    if (x < 0 || x >= SX || y < 0 || y >= SY) return 0.0f;
    return img[(size_t)b * SX * SY + (size_t)x * SY + y];
}

// Stage 1: Sobel -> mag (unnormalized), initial tangent field, per-block max.
// NOTE: runs under the harness 256MB poison-fill writeback drain (~42us of HBM
// write traffic) — its wall time is ~45us regardless of content.
__global__ void k_sobel(const float* __restrict__ img, float* __restrict__ mag,
                        float2* __restrict__ tang, float* __restrict__ partial) {
#pragma clang fp contract(off)
    int yi = blockIdx.x * blockDim.x + threadIdx.x;
    int xi = blockIdx.y;
    int b  = blockIdx.z;

    float v00 = img_at(img, b, xi - 1, yi - 1);
    float v01 = img_at(img, b, xi - 1, yi    );
    float v02 = img_at(img, b, xi - 1, yi + 1);
    float v10 = img_at(img, b, xi,     yi - 1);
    float v12 = img_at(img, b, xi,     yi + 1);
    float v20 = img_at(img, b, xi + 1, yi - 1);
    float v21 = img_at(img, b, xi + 1, yi    );
    float v22 = img_at(img, b, xi + 1, yi + 1);

    float s0 = (-1.0f * v00);
    s0 = s0 + (-2.0f * v01);
    s0 = s0 + (-1.0f * v02);
    s0 = s0 + ( 1.0f * v20);
    s0 = s0 + ( 2.0f * v21);
    s0 = s0 + ( 1.0f * v22);
    float s1 = (-1.0f * v00);
    s1 = s1 + ( 1.0f * v02);
    s1 = s1 + (-2.0f * v10);
    s1 = s1 + ( 2.0f * v12);
    s1 = s1 + (-1.0f * v20);
    s1 = s1 + ( 1.0f * v22);

    float m = sqrtf((s0 * s0) + (s1 * s1));
    size_t idx = (size_t)b * SX * SY + (size_t)xi * SY + yi;
    mag[idx] = m;

    float tx = -s1, ty = s0;
    float n = sqrtf((tx * tx) + (ty * ty));
    float d = (n == 0.0f) ? 1.0f : n;
    tang[idx] = make_float2(tx / d, ty / d);

    float wm = m;
    for (int off = 32; off > 0; off >>= 1) wm = fmaxf(wm, __shfl_down(wm, off, 64));
    __shared__ float red[4];
    int lane = threadIdx.x & 63;
    int wid  = threadIdx.x >> 6;
    if (lane == 0) red[wid] = wm;
    __syncthreads();
    if (threadIdx.x == 0) {
        float bm = fmaxf(fmaxf(red[0], red[1]), fmaxf(red[2], red[3]));
        int bid = blockIdx.x + gridDim.x * (blockIdx.y + gridDim.y * blockIdx.z);
        partial[bid] = bm;
    }
}

// Stage 2: reduce per-block partials -> global max bits (one block).
__global__ void k_reduce(const float* __restrict__ partial, unsigned int* __restrict__ maxbits) {
    float m = 0.0f;
    for (int i = threadIdx.x; i < NBLOCKS; i += 256) m = fmaxf(m, partial[i]);
    for (int off = 32; off > 0; off >>= 1) m = fmaxf(m, __shfl_down(m, off, 64));
    __shared__ float red[4];
    int lane = threadIdx.x & 63;
    int wid  = threadIdx.x >> 6;
    if (lane == 0) red[wid] = m;
    __syncthreads();
    if (threadIdx.x == 0) {
        float bm = fmaxf(fmaxf(red[0], red[1]), fmaxf(red[2], red[3]));
        *maxbits = __float_as_uint(bm);
    }
}

// Stage 2b (fallback only): mag /= max(mag)
__global__ void k_norm(float* __restrict__ mag, const unsigned int* __restrict__ maxbits) {
    int i = blockIdx.x * blockDim.x + threadIdx.x;
    float mx = __uint_as_float(*maxbits);
    mag[i] = mag[i] / mx;
}

// Precompute tanh difference fields; normalization fused.
__global__ void k_tanh(const float* __restrict__ mag, const unsigned int* __restrict__ maxbits,
                       float* __restrict__ TV, float* __restrict__ TH) {
#pragma clang fp contract(off)
    int yi = blockIdx.x * blockDim.x + threadIdx.x;
    int xi = blockIdx.y;
    int b  = blockIdx.z;
    size_t base = (size_t)b * SX * SY;
    size_t idx  = base + (size_t)xi * SY + yi;
    float mx = __uint_as_float(*maxbits);
    float cm = mag[idx] / mx;
#pragma unroll
    for (int k = 1; k <= 5; ++k) {
        if (xi + k < SX) {
            float nm = mag[idx + (size_t)k * SY] / mx;
            TV[(size_t)(k - 1) * NPIX + idx] = fast_tanh_f32(nm - cm);
        }
    }
#pragma unroll
    for (int k = 1; k <= 5; ++k) {
        if (yi + k < SY) {
            float nm = mag[idx + k] / mx;
            TH[(size_t)(k - 1) * NPIX + idx] = fast_tanh_f32(nm - cm);
        }
    }
}

// Stage 3 fused: one ETF iteration (V-pass then H-pass) per kernel.
// Block computes a 4(x) x 64(y) H-output tile. V-pass is computed in LDS over
// the y-extended range [y0-5, y0+69) (1.16x redundant V compute) with
// arithmetic identical to the split V kernel; H-pass reads the LDS V field
// with arithmetic identical to the split H kernel -> bit-exact.
// Eliminates the 8MB V-field round trip + one launch per iteration.
// LDS 31.7 KB -> 5 blocks/CU (20 waves). DoG fused on last iteration.
#define FTX 4
#define FTY 64
#define ETY (FTY + 2 * MU)       // 74 V columns computed
#define SCOL (FTY + 16)          // 80 staged cols, base gy = y0 - 8
__global__ __launch_bounds__(256) void k_etf_vh(const float2* __restrict__ tsrc,
                                                float2* __restrict__ tdst,
                                                const float* __restrict__ TV,
                                                const float* __restrict__ TH,
                                                const float* __restrict__ img,
                                                float* __restrict__ dogout,
                                                DogW dw, int do_dog) {
#pragma clang fp contract(off)
    int tid = threadIdx.x;
    int y0 = blockIdx.x * FTY;
    int x0 = blockIdx.y * FTX;
    int b  = blockIdx.z;
    size_t base = (size_t)b * SX * SY;

    __shared__ __align__(16) float2 sT[FTX + 2 * MU][SCOL];     // 14 x 80 f2 (8960 B)
    __shared__ __align__(16) float  sTV[5][FTX + MU][SCOL];     // 5 x 9 x 80 (14400 B)
    __shared__ __align__(16) float2 sV[FTX][SCOL];              // 4 x 80 f2  (2560 B)
    __shared__ __align__(16) float  sTH[5][FTX][FTY + 8];       // 5 x 4 x 72 (5760 B)

    // stage tsrc rows [x0-5, x0+9) x cols [y0-8, y0+72): 14 * 40 float4
    for (int i = tid; i < (FTX + 2 * MU) * (SCOL / 2); i += 256) {
        int r  = i / (SCOL / 2);
        int c  = i % (SCOL / 2);           // float4 idx; covers 2 float2 cols
        int gx = x0 - MU + r;
        int gy = y0 - 8 + 2 * c;
        if (gx >= 0 && gx < SX && gy >= 0 && gy < SY)
            ((float4*)&sT[r][0])[c] =
                *((const float4*)(tsrc + base + (size_t)gx * SY + gy));
    }
    // stage TV planes rows [x0-5, x0+4) x cols [y0-8, y0+72): 5*9*20 float4
    for (int i = tid; i < 5 * (FTX + MU) * (SCOL / 4); i += 256) {
        int j   = i / ((FTX + MU) * (SCOL / 4));
        int rem = i - j * ((FTX + MU) * (SCOL / 4));
        int r   = rem / (SCOL / 4);
        int c   = rem % (SCOL / 4);        // float4 idx; covers 4 float cols
        int gx  = x0 - MU + r;
        int gy  = y0 - 8 + 4 * c;
        if (gx >= 0 && gx < SX && gy >= 0 && gy < SY)
            ((float4*)&sTV[j][r][0])[c] =
                *((const float4*)(TV + (size_t)j * NPIX + base + (size_t)gx * SY + gy));
    }
    // stage TH planes rows [x0, x0+4) x cols [y0-8, y0+64): 5*4*18 float4
    for (int i = tid; i < 5 * FTX * ((FTY + 8) / 4); i += 256) {
        int j   = i / (FTX * ((FTY + 8) / 4));
        int rem = i - j * (FTX * ((FTY + 8) / 4));
        int r   = rem / ((FTY + 8) / 4);
        int c   = rem % ((FTY + 8) / 4);
        int gx  = x0 + r;
        int gy  = y0 - 8 + 4 * c;
        if (gy >= 0)   // gx always valid; right edge never exceeds SY
            ((float4*)&sTH[j][r][0])[c] =
                *((const float4*)(TH + (size_t)j * NPIX + base + (size_t)gx * SY + gy));
    }
    __syncthreads();

    // ---- V-pass into sV (cols [y0-5, y0+69); garbage at invalid cols is
    //      never read by the guarded H-pass) ----
    for (int p = tid; p < FTX * ETY; p += 256) {
        int r  = p / ETY;
        int e  = p % ETY;
        int xi = x0 + r;
        int c  = e + 3;                    // staged-col index (base y0-8)
        float2 ct = sT[r + MU][c];
        float sx = 0.0f, sy = 0.0f;
#pragma unroll
        for (int k = -MU; k <= MU; ++k) {
            int nx = xi + k;
            if (nx < 0 || nx >= SX) continue;
            float2 nt = sT[r + MU + k][c];
            float th;
            if (k > 0)      th =  sTV[k - 1][r + MU][c];
            else if (k < 0) th = -sTV[-k - 1][r + MU + k][c];
            else            th =  0.0f;
            float dot = (ct.x * nt.x) + (ct.y * nt.y);
            float w   = ((th + 1.0f) * dot) * 0.5f;
            sx = sx + (nt.x * w);
            sy = sy + (nt.y * w);
        }
        float n = sqrtf((sx * sx) + (sy * sy));
        float d = (n == 0.0f) ? 1.0f : n;
        sV[r][c] = make_float2(sx / d, sy / d);
    }
    __syncthreads();

    // ---- H-pass: 4 x 64 outputs, one per thread ----
    {
        int r  = tid >> 6;                 // 0..3
        int yl = tid & 63;
        int xi = x0 + r;
        int yi = y0 + yl;
        size_t rowbase = base + (size_t)xi * SY;

        float2 ct = sV[r][yl + 8];
        float sx = 0.0f, sy = 0.0f;
#pragma unroll
        for (int k = -MU; k <= MU; ++k) {
            int ny = yi + k;
            if (ny < 0 || ny >= SY) continue;
            float2 nt = sV[r][yl + 8 + k];
            float th;
            if (k > 0)      th =  sTH[k - 1][r][yl + 8];
            else if (k < 0) th = -sTH[-k - 1][r][yl + 8 + k];
            else            th =  0.0f;
            float dot = (ct.x * nt.x) + (ct.y * nt.y);
            float w   = ((th + 1.0f) * dot) * 0.5f;
            sx = sx + (nt.x * w);
            sy = sy + (nt.y * w);
        }
        float n = sqrtf((sx * sx) + (sy * sy));
        float d = (n == 0.0f) ? 1.0f : n;
        float ex = sx / d;
        float ey = sy / d;
        tdst[rowbase + yi] = make_float2(ex, ey);

        if (do_dog) {
            float perx = -ey;
            float pery =  ex;
            float xf = (float)xi, yf = (float)yi;
            float acc = 0.0f;
#pragma unroll
            for (int t = -3; t <= 3; ++t) {
                float tf  = (float)t;
                float ptx = xf + (perx * tf);
                float pty = yf + (pery * tf);
                int px = (int)rintf(fminf(fmaxf(ptx, 0.0f), (float)(SX - 1)));
                int py = (int)rintf(fminf(fmaxf(pty, 0.0f), (float)(SY - 1)));
                float il = img[base + (size_t)px * SY + py];
                acc = acc + (il * dw.g[t + 3]);
            }
            dogout[rowbase + yi] = acc / dw.tw;
        }
    }
}

// Stage 3 (fallback, inline ocml tanh) — only if workspace is too small.
__global__ void k_etf(const float2* __restrict__ tsrc, float2* __restrict__ tdst,
                      const float* __restrict__ mag, int vert) {
#pragma clang fp contract(off)
    int yi = blockIdx.x * blockDim.x + threadIdx.x;
    int xi = blockIdx.y;
    int b  = blockIdx.z;
    size_t base = (size_t)b * SX * SY;
    size_t idx  = base + (size_t)xi * SY + yi;

    float  cm = mag[idx];
    float2 ct = tsrc[idx];

    float sx = 0.0f, sy = 0.0f;
    for (int k = -MU; k <= MU; ++k) {
        int nx = xi + (vert ? k : 0);
        int ny = yi + (vert ? 0 : k);
        if (nx < 0 || nx >= SX || ny < 0 || ny >= SY) continue;
        size_t nidx = base + (size_t)nx * SY + ny;
        float  nm = mag[nidx];
        float2 nt = tsrc[nidx];
        float dot = (ct.x * nt.x) + (ct.y * nt.y);
        float th  = (float)tanh((double)(nm - cm));
        float w   = ((th + 1.0f) * dot) * 0.5f;
        sx = sx + (nt.x * w);
        sy = sy + (nt.y * w);
    }
    float n = sqrtf((sx * sx) + (sy * sy));
    float d = (n == 0.0f) ? 1.0f : n;
    tdst[idx] = make_float2(sx / d, sy / d);
}

// Stage 4 (fallback only): DoG along the perpendicular of the ETF
__global__ void k_dog(const float* __restrict__ img, const float2* __restrict__ etf,
                      float* __restrict__ dog, DogW w) {
#pragma clang fp contract(off)
    int yi = blockIdx.x * blockDim.x + threadIdx.x;
    int xi = blockIdx.y;
    int b  = blockIdx.z;
    size_t base = (size_t)b * SX * SY;
    size_t idx  = base + (size_t)xi * SY + yi;

    float2 e = etf[idx];
    float perx = -e.y;
    float pery =  e.x;
    float xf = (float)xi, yf = (float)yi;

    float acc = 0.0f;
#pragma unroll
    for (int t = -3; t <= 3; ++t) {
        float tf  = (float)t;
        float ptx = xf + (perx * tf);
        float pty = yf + (pery * tf);
        int px = (int)rintf(fminf(fmaxf(ptx, 0.0f), (float)(SX - 1)));
        int py = (int)rintf(fminf(fmaxf(pty, 0.0f), (float)(SY - 1)));
        float il = img[base + (size_t)px * SY + py];
        acc = acc + (il * w.g[t + 3]);
    }
    dog[idx] = acc / w.tw;
}

// Stage 5: FDoG. Two independent dependent-load chains walked interleaved.
__global__ void k_fdog(const float* __restrict__ dog, const float2* __restrict__ etf,
                       int* __restrict__ out, FdogW w) {
#pragma clang fp contract(off)
    int yi = blockIdx.x * blockDim.x + threadIdx.x;
    int xi = blockIdx.y;
    int b  = blockIdx.z;
    size_t base = (size_t)b * SX * SY;
    size_t idx  = base + (size_t)xi * SY + yi;

    float d1[9];
    float d2[10];
    float2 e0 = etf[idx];
    float2 e1 = e0, e2 = e0;
    int p1x = xi, p1y = yi;
    int p2x = xi, p2y = yi;
    d2[0] = dog[idx];

#pragma unroll
    for (int s = 1; s <= 9; ++s) {
        float fx1 = (float)p1x + (e1.x * -1.0f);
        float fy1 = (float)p1y + (e1.y * -1.0f);
        p1x = (int)rintf(fminf(fmaxf(fx1, 0.0f), (float)(SX - 1)));
        p1y = (int)rintf(fminf(fmaxf(fy1, 0.0f), (float)(SY - 1)));
        size_t i1 = base + (size_t)p1x * SY + p1y;
        float fx2 = (float)p2x + (e2.x * 1.0f);
        float fy2 = (float)p2y + (e2.y * 1.0f);
        p2x = (int)rintf(fminf(fmaxf(fx2, 0.0f), (float)(SX - 1)));
        p2y = (int)rintf(fminf(fmaxf(fy2, 0.0f), (float)(SY - 1)));
        size_t i2 = base + (size_t)p2x * SY + p2y;

        d1[s - 1] = dog[i1];
        d2[s]     = dog[i2];
        if (s < 9) {
            e1 = etf[i1];
            e2 = etf[i2];
        }
    }

    float acc = 0.0f;
#pragma unroll
    for (int s = 1; s <= 9; ++s) acc = acc + (d1[s - 1] * w.g[s]);
    acc = acc + (d2[0] * w.g[0]);
#pragma unroll
    for (int s = 1; s <= 9; ++s) acc = acc + (d2[s] * w.g[s]);

    float fv = acc / w.tw;
    float th = 1.0f + fast_tanh_f32(fv);
    out[idx] = ((fv < 0.0f) && (th < 0.7f)) ? 0 : 1;
}

static double gpdf(double v, double sig) {
    return exp(-(v * v) / (2.0 * sig * sig)) / (sqrt(2.0 * M_PI) * sig);
}

extern "C" void kernel_launch(void* const* d_in, const int* in_sizes, int n_in,
                              void* d_out, int out_size, void* d_ws, size_t ws_size,
                              hipStream_t stream) {
    const float* img = (const float*)d_in[0];
    int* out = (int*)d_out;
    char* ws = (char*)d_ws;

    // Fast-path workspace layout (60 MB + 16 KB + 4 B):
    //   mag [0,4MB) (dog reuses after k_tanh) | tA [4,12) | tB [12,20)
    //   TV [20,40) | TH [40,60) | partial [60MB,+16KB) | maxbits [+4)
    const size_t need = (size_t)60 * MB + NBLOCKS * sizeof(float) + 4;
    bool fast = ws_size >= need;

    float*  mag = (float*)(ws);
    float2* tA  = (float2*)(ws + (size_t)4  * MB);
    float2* tB  = (float2*)(ws + (size_t)12 * MB);
    float*  TV  = (float*)(ws + (size_t)20 * MB);
    float*  TH  = (float*)(ws + (size_t)40 * MB);
    size_t  tail = fast ? (size_t)60 * MB : (size_t)20 * MB;
    float*        partial = (float*)(ws + tail);
    unsigned int* maxbits = (unsigned int*)(ws + tail + NBLOCKS * sizeof(float));

    dim3 blk(256, 1, 1);
    dim3 grd(SY / 256, SX, BN);
    dim3 vhgrd(SY / FTY, SX / FTX, BN);   // 8 x 128 x 4 = 4096

    DogW dw;
    {
        double tw = 0.0;
        for (int t = -3; t <= 3; ++t) {
            double g = gpdf((double)t, 1.0) - 0.99 * gpdf((double)t, 1.6);
            dw.g[t + 3] = (float)g;
            tw += g;
        }
        dw.tw = (float)tw;
    }
    FdogW fw;
    {
        for (int s = 0; s <= 9; ++s) fw.g[s] = (float)gpdf((double)s, 3.0);
        double tw = 0.0;
        for (int s = 1; s <= 9; ++s) tw += gpdf((double)s, 3.0);
        for (int s = 0; s <= 9; ++s) tw += gpdf((double)s, 3.0);
        fw.tw = (float)tw;
    }

    k_sobel<<<grd, blk, 0, stream>>>(img, mag, tA, partial);
    k_reduce<<<1, 256, 0, stream>>>(partial, maxbits);

    float2* src = tA;
    float2* dst = tB;
    if (fast) {
        float* dogbuf = mag;   // mag is dead after k_tanh; reuse as DoG output
        k_tanh<<<grd, blk, 0, stream>>>(mag, maxbits, TV, TH);
        for (int it = 0; it < 3; ++it) {
            k_etf_vh<<<vhgrd, blk, 0, stream>>>(src, dst, TV, TH, img, dogbuf, dw, it == 2);
            { float2* t = src; src = dst; dst = t; }
        }
        // src holds final ETF; dogbuf holds DoG
        k_fdog<<<grd, blk, 0, stream>>>(dogbuf, src, out, fw);
    } else {
        k_norm<<<NPIX / 256, 256, 0, stream>>>(mag, maxbits);
        for (int it = 0; it < 3; ++it) {
            k_etf<<<grd, blk, 0, stream>>>(src, dst, mag, 1);
            { float2* t = src; src = dst; dst = t; }
            k_etf<<<grd, blk, 0, stream>>>(src, dst, mag, 0);
            { float2* t = src; src = dst; dst = t; }
        }
        float* dogbuf = (src == tA) ? (float*)tB : (float*)tA;
        k_dog<<<grd, blk, 0, stream>>>(img, src, dogbuf, dw);
        k_fdog<<<grd, blk, 0, stream>>>(dogbuf, src, out, fw);
    }
}

// Round 5
// 189.400 us; speedup vs baseline: 4.7436x; 1.1270x over previous
//
#include <hip/hip_runtime.h>
#include <math.h>

#pragma clang fp contract(off)

#define BN 4
#define SX 512
#define SY 512
#define NPIX (BN * SX * SY)
#define MU 5
#define MB (1024 * 1024)
#define SOB_BLOCKS (NPIX / 1024)   // 1024 sobel blocks (4 px/thread)

struct DogW  { float g[7];  float tw; };
struct FdogW { float g[10]; float tw; };

// tanh via expm1 identity: tanh(d) = expm1(2|d|) / (expm1(2|d|) + 2), odd.
__device__ __forceinline__ float fast_tanh_f32(float dF) {
    double d = (double)dF;
    double y = fabs(d);
    double t = expm1(2.0 * y);
    double r = t / (t + 2.0);
    if (y > 350.0) r = 1.0;
    return (float)copysign(r, d);
}

__device__ __forceinline__ float img_at(const float* __restrict__ img, int b, int x, int y) {
    if (x < 0 || x >= SX || y < 0 || y >= SY) return 0.0f;
    return img[(size_t)b * SX * SY + (size_t)x * SY + y];
}

// Stage 1: Sobel -> mag (unnormalized), initial tangent, per-block max.
// Vectorized: 4 px/thread from 3 float4 row loads + 6 guarded scalars
// (2.25 loads/px vs 8 scalar). Per-pixel expression order identical to the
// scalar version -> bit-exact. Max reduce is exact (fmax associative).
__global__ __launch_bounds__(256) void k_sobel(const float* __restrict__ img,
                                               float* __restrict__ mag,
                                               float2* __restrict__ tang,
                                               float* __restrict__ partial) {
#pragma clang fp contract(off)
    int tid = threadIdx.x;
    size_t pixbase = (size_t)blockIdx.x * 1024 + (size_t)tid * 4;
    int b  = (int)(pixbase >> 18);          // / (512*512)
    int p  = (int)(pixbase & 262143);
    int xi = p >> 9;
    int yi = p & 511;
    size_t base = (size_t)b * SX * SY;
    size_t idx  = base + (size_t)xi * SY + yi;

    bool xm = (xi - 1 >= 0);
    bool xp = (xi + 1 < SX);
    const float* rowm = img + base + (size_t)(xi - 1) * SY;
    const float* row0 = img + base + (size_t)xi * SY;
    const float* rowp = img + base + (size_t)(xi + 1) * SY;

    float4 a4 = make_float4(0.f, 0.f, 0.f, 0.f);
    float4 c4 = make_float4(0.f, 0.f, 0.f, 0.f);
    float4 b4 = *(const float4*)(row0 + yi);
    if (xm) a4 = *(const float4*)(rowm + yi);
    if (xp) c4 = *(const float4*)(rowp + yi);

    float aL = 0.f, aR = 0.f, bL = 0.f, bR = 0.f, cL = 0.f, cR = 0.f;
    if (yi > 0) {
        bL = row0[yi - 1];
        if (xm) aL = rowm[yi - 1];
        if (xp) cL = rowp[yi - 1];
    }
    if (yi + 4 < SY) {
        bR = row0[yi + 4];
        if (xm) aR = rowm[yi + 4];
        if (xp) cR = rowp[yi + 4];
    }

    float a[6] = { aL, a4.x, a4.y, a4.z, a4.w, aR };   // cols yi-1 .. yi+4
    float bb[6] = { bL, b4.x, b4.y, b4.z, b4.w, bR };
    float c[6] = { cL, c4.x, c4.y, c4.z, c4.w, cR };

    float4 m4;
    float4 t01, t23;
    float wm = 0.0f;
#pragma unroll
    for (int j = 0; j < 4; ++j) {
        float v00 = a[j];     // (xi-1, yi+j-1)
        float v01 = a[j + 1];
        float v02 = a[j + 2];
        float v10 = bb[j];
        float v12 = bb[j + 2];
        float v20 = c[j];
        float v21 = c[j + 1];
        float v22 = c[j + 2];

        float s0 = (-1.0f * v00);
        s0 = s0 + (-2.0f * v01);
        s0 = s0 + (-1.0f * v02);
        s0 = s0 + ( 1.0f * v20);
        s0 = s0 + ( 2.0f * v21);
        s0 = s0 + ( 1.0f * v22);
        float s1 = (-1.0f * v00);
        s1 = s1 + ( 1.0f * v02);
        s1 = s1 + (-2.0f * v10);
        s1 = s1 + ( 2.0f * v12);
        s1 = s1 + (-1.0f * v20);
        s1 = s1 + ( 1.0f * v22);

        float m = sqrtf((s0 * s0) + (s1 * s1));
        float tx = -s1, ty = s0;
        float n = sqrtf((tx * tx) + (ty * ty));
        float d = (n == 0.0f) ? 1.0f : n;
        float ex = tx / d;
        float ey = ty / d;

        (&m4.x)[j] = m;
        if (j == 0) { t01.x = ex; t01.y = ey; }
        if (j == 1) { t01.z = ex; t01.w = ey; }
        if (j == 2) { t23.x = ex; t23.y = ey; }
        if (j == 3) { t23.z = ex; t23.w = ey; }
        wm = fmaxf(wm, m);
    }
    *(float4*)(mag + idx) = m4;
    ((float4*)(tang + idx))[0] = t01;
    ((float4*)(tang + idx))[1] = t23;

    for (int off = 32; off > 0; off >>= 1) wm = fmaxf(wm, __shfl_down(wm, off, 64));
    __shared__ float red[4];
    int lane = tid & 63;
    int wid  = tid >> 6;
    if (lane == 0) red[wid] = wm;
    __syncthreads();
    if (tid == 0)
        partial[blockIdx.x] = fmaxf(fmaxf(red[0], red[1]), fmaxf(red[2], red[3]));
}

// Stage 2 (fallback only): reduce partials -> global max bits (one block).
__global__ void k_reduce(const float* __restrict__ partial, unsigned int* __restrict__ maxbits) {
    float m = 0.0f;
    for (int i = threadIdx.x; i < SOB_BLOCKS; i += 256) m = fmaxf(m, partial[i]);
    for (int off = 32; off > 0; off >>= 1) m = fmaxf(m, __shfl_down(m, off, 64));
    __shared__ float red[4];
    int lane = threadIdx.x & 63;
    int wid  = threadIdx.x >> 6;
    if (lane == 0) red[wid] = m;
    __syncthreads();
    if (threadIdx.x == 0) {
        float bm = fmaxf(fmaxf(red[0], red[1]), fmaxf(red[2], red[3]));
        *maxbits = __float_as_uint(bm);
    }
}

// Stage 2b (fallback only): mag /= max(mag)
__global__ void k_norm(float* __restrict__ mag, const unsigned int* __restrict__ maxbits) {
    int i = blockIdx.x * blockDim.x + threadIdx.x;
    float mx = __uint_as_float(*maxbits);
    mag[i] = mag[i] / mx;
}

// Stage 2+3 fused: every block redundantly reduces the 1024 partials (L2-hit,
// ~1us overlapped) -> mx in-register; then tanh difference fields with
// normalization fused. fmax is exact -> mx bit-identical to 1-block reduce.
__global__ void k_tanh(const float* __restrict__ mag, const float* __restrict__ partial,
                       float* __restrict__ TV, float* __restrict__ TH) {
#pragma clang fp contract(off)
    int tid = threadIdx.x;
    float m2 = 0.0f;
    for (int i = tid; i < SOB_BLOCKS; i += 256) m2 = fmaxf(m2, partial[i]);
    for (int off = 32; off > 0; off >>= 1) m2 = fmaxf(m2, __shfl_down(m2, off, 64));
    __shared__ float red[4];
    int lane = tid & 63;
    int wid  = tid >> 6;
    if (lane == 0) red[wid] = m2;
    __syncthreads();
    const float mx = fmaxf(fmaxf(red[0], red[1]), fmaxf(red[2], red[3]));

    int yi = blockIdx.x * blockDim.x + tid;
    int xi = blockIdx.y;
    int b  = blockIdx.z;
    size_t base = (size_t)b * SX * SY;
    size_t idx  = base + (size_t)xi * SY + yi;
    float cm = mag[idx] / mx;
#pragma unroll
    for (int k = 1; k <= 5; ++k) {
        if (xi + k < SX) {
            float nm = mag[idx + (size_t)k * SY] / mx;
            TV[(size_t)(k - 1) * NPIX + idx] = fast_tanh_f32(nm - cm);
        }
    }
#pragma unroll
    for (int k = 1; k <= 5; ++k) {
        if (yi + k < SY) {
            float nm = mag[idx + k] / mx;
            TH[(size_t)(k - 1) * NPIX + idx] = fast_tanh_f32(nm - cm);
        }
    }
}

// Stage 3a: V-pass. Tile 32(y) x 16(x); 256 threads, 2 output rows/thread.
// LDS = 19.6 KB -> full 32-wave occupancy; halo: tsrc 1.63x, TV 1.31x.
#define VTY 32
#define VTX 16
__global__ __launch_bounds__(256) void k_etf_v(const float2* __restrict__ tsrc,
                                               float2* __restrict__ tdst,
                                               const float* __restrict__ TV) {
#pragma clang fp contract(off)
    int ty  = threadIdx.x & 31;
    int txw = threadIdx.x >> 5;
    int y0 = blockIdx.x * VTY;
    int x0 = blockIdx.y * VTX;
    int b  = blockIdx.z;
    size_t base = (size_t)b * SX * SY;

    __shared__ __align__(16) float2 sT[VTX + 2 * MU][VTY];     // 26 x 32 f2 (6.5 KB)
    __shared__ __align__(16) float  sTV[5][VTX + MU][VTY];     // 5 x 21 x 32 (13.1 KB)

    int tid = threadIdx.x;
    for (int i = tid; i < (VTX + 2 * MU) * (VTY / 4) * 2; i += 256) {
        int r = i >> 4;
        int c = i & 15;
        int gx = x0 - MU + r;
        if (gx >= 0 && gx < SX)
            ((float4*)&sT[r][0])[c] = ((const float4*)(tsrc + base + (size_t)gx * SY + y0))[c];
    }
    for (int i = tid; i < 5 * (VTX + MU) * (VTY / 4); i += 256) {
        int j   = i / ((VTX + MU) * (VTY / 4));
        int rem = i - j * ((VTX + MU) * (VTY / 4));
        int r   = rem >> 3;
        int c   = rem & 7;
        int gx  = x0 - MU + r;
        if (gx >= 0 && gx < SX)
            ((float4*)&sTV[j][r][0])[c] =
                ((const float4*)(TV + (size_t)j * NPIX + base + (size_t)gx * SY + y0))[c];
    }
    __syncthreads();

    int yi = y0 + ty;
#pragma unroll
    for (int sub = 0; sub < 2; ++sub) {
        int tx = txw + (sub << 3);
        int xi = x0 + tx;
        size_t idx = base + (size_t)xi * SY + yi;

        float2 ct = sT[tx + MU][ty];
        float sx = 0.0f, sy = 0.0f;
#pragma unroll
        for (int k = -MU; k <= MU; ++k) {
            int nx = xi + k;
            if (nx < 0 || nx >= SX) continue;
            float2 nt = sT[tx + MU + k][ty];
            float th;
            if (k > 0)      th =  sTV[k - 1][tx + MU][ty];
            else if (k < 0) th = -sTV[-k - 1][tx + MU + k][ty];
            else            th =  0.0f;
            float dot = (ct.x * nt.x) + (ct.y * nt.y);
            float w   = ((th + 1.0f) * dot) * 0.5f;
            sx = sx + (nt.x * w);
            sy = sy + (nt.y * w);
        }
        float n = sqrtf((sx * sx) + (sy * sy));
        float d = (n == 0.0f) ? 1.0f : n;
        tdst[idx] = make_float2(sx / d, sy / d);
    }
}

// Stage 3b: H-pass. One block per image row; DoG fused on last iteration.
__global__ __launch_bounds__(256) void k_etf_h(const float2* __restrict__ tsrc,
                                               float2* __restrict__ tdst,
                                               const float* __restrict__ TH,
                                               const float* __restrict__ img,
                                               float* __restrict__ dogout,
                                               DogW dw, int do_dog) {
#pragma clang fp contract(off)
    int tid = threadIdx.x;
    int xi  = blockIdx.y;
    int b   = blockIdx.z;
    size_t base    = (size_t)b * SX * SY;
    size_t rowbase = base + (size_t)xi * SY;

    __shared__ __align__(16) float2 sT[SY];        // 4 KB
    __shared__ __align__(16) float  sTH[5][SY];    // 10 KB

    ((float4*)sT)[tid] = ((const float4*)(tsrc + rowbase))[tid];
    for (int i = tid; i < 5 * (SY / 4); i += 256) {
        int j = i >> 7;
        int c = i & 127;
        ((float4*)&sTH[0][0])[i] = ((const float4*)(TH + (size_t)j * NPIX + rowbase))[c];
    }
    __syncthreads();

#pragma unroll
    for (int half = 0; half < 2; ++half) {
        int yi = tid + half * 256;
        float2 ct = sT[yi];
        float sx = 0.0f, sy = 0.0f;
#pragma unroll
        for (int k = -MU; k <= MU; ++k) {
            int ny = yi + k;
            if (ny < 0 || ny >= SY) continue;
            float2 nt = sT[ny];
            float th;
            if (k > 0)      th =  sTH[k - 1][yi];
            else if (k < 0) th = -sTH[-k - 1][ny];
            else            th =  0.0f;
            float dot = (ct.x * nt.x) + (ct.y * nt.y);
            float w   = ((th + 1.0f) * dot) * 0.5f;
            sx = sx + (nt.x * w);
            sy = sy + (nt.y * w);
        }
        float n = sqrtf((sx * sx) + (sy * sy));
        float d = (n == 0.0f) ? 1.0f : n;
        float ex = sx / d;
        float ey = sy / d;
        tdst[rowbase + yi] = make_float2(ex, ey);

        if (do_dog) {
            float perx = -ey;
            float pery =  ex;
            float xf = (float)xi, yf = (float)yi;
            float acc = 0.0f;
#pragma unroll
            for (int t = -3; t <= 3; ++t) {
                float tf  = (float)t;
                float ptx = xf + (perx * tf);
                float pty = yf + (pery * tf);
                int px = (int)rintf(fminf(fmaxf(ptx, 0.0f), (float)(SX - 1)));
                int py = (int)rintf(fminf(fmaxf(pty, 0.0f), (float)(SY - 1)));
                float il = img[base + (size_t)px * SY + py];
                acc = acc + (il * dw.g[t + 3]);
            }
            dogout[rowbase + yi] = acc / dw.tw;
        }
    }
}

// Stage 3 (fallback, inline ocml tanh) — only if workspace is too small.
__global__ void k_etf(const float2* __restrict__ tsrc, float2* __restrict__ tdst,
                      const float* __restrict__ mag, int vert) {
#pragma clang fp contract(off)
    int yi = blockIdx.x * blockDim.x + threadIdx.x;
    int xi = blockIdx.y;
    int b  = blockIdx.z;
    size_t base = (size_t)b * SX * SY;
    size_t idx  = base + (size_t)xi * SY + yi;

    float  cm = mag[idx];
    float2 ct = tsrc[idx];

    float sx = 0.0f, sy = 0.0f;
    for (int k = -MU; k <= MU; ++k) {
        int nx = xi + (vert ? k : 0);
        int ny = yi + (vert ? 0 : k);
        if (nx < 0 || nx >= SX || ny < 0 || ny >= SY) continue;
        size_t nidx = base + (size_t)nx * SY + ny;
        float  nm = mag[nidx];
        float2 nt = tsrc[nidx];
        float dot = (ct.x * nt.x) + (ct.y * nt.y);
        float th  = (float)tanh((double)(nm - cm));
        float w   = ((th + 1.0f) * dot) * 0.5f;
        sx = sx + (nt.x * w);
        sy = sy + (nt.y * w);
    }
    float n = sqrtf((sx * sx) + (sy * sy));
    float d = (n == 0.0f) ? 1.0f : n;
    tdst[idx] = make_float2(sx / d, sy / d);
}

// Stage 4 (fallback only): DoG along the perpendicular of the ETF
__global__ void k_dog(const float* __restrict__ img, const float2* __restrict__ etf,
                      float* __restrict__ dog, DogW w) {
#pragma clang fp contract(off)
    int yi = blockIdx.x * blockDim.x + threadIdx.x;
    int xi = blockIdx.y;
    int b  = blockIdx.z;
    size_t base = (size_t)b * SX * SY;
    size_t idx  = base + (size_t)xi * SY + yi;

    float2 e = etf[idx];
    float perx = -e.y;
    float pery =  e.x;
    float xf = (float)xi, yf = (float)yi;

    float acc = 0.0f;
#pragma unroll
    for (int t = -3; t <= 3; ++t) {
        float tf  = (float)t;
        float ptx = xf + (perx * tf);
        float pty = yf + (pery * tf);
        int px = (int)rintf(fminf(fmaxf(ptx, 0.0f), (float)(SX - 1)));
        int py = (int)rintf(fminf(fmaxf(pty, 0.0f), (float)(SY - 1)));
        float il = img[base + (size_t)px * SY + py];
        acc = acc + (il * w.g[t + 3]);
    }
    dog[idx] = acc / w.tw;
}

// Stage 5: FDoG. Two independent dependent-load chains walked interleaved.
__global__ void k_fdog(const float* __restrict__ dog, const float2* __restrict__ etf,
                       int* __restrict__ out, FdogW w) {
#pragma clang fp contract(off)
    int yi = blockIdx.x * blockDim.x + threadIdx.x;
    int xi = blockIdx.y;
    int b  = blockIdx.z;
    size_t base = (size_t)b * SX * SY;
    size_t idx  = base + (size_t)xi * SY + yi;

    float d1[9];
    float d2[10];
    float2 e0 = etf[idx];
    float2 e1 = e0, e2 = e0;
    int p1x = xi, p1y = yi;
    int p2x = xi, p2y = yi;
    d2[0] = dog[idx];

#pragma unroll
    for (int s = 1; s <= 9; ++s) {
        float fx1 = (float)p1x + (e1.x * -1.0f);
        float fy1 = (float)p1y + (e1.y * -1.0f);
        p1x = (int)rintf(fminf(fmaxf(fx1, 0.0f), (float)(SX - 1)));
        p1y = (int)rintf(fminf(fmaxf(fy1, 0.0f), (float)(SY - 1)));
        size_t i1 = base + (size_t)p1x * SY + p1y;
        float fx2 = (float)p2x + (e2.x * 1.0f);
        float fy2 = (float)p2y + (e2.y * 1.0f);
        p2x = (int)rintf(fminf(fmaxf(fx2, 0.0f), (float)(SX - 1)));
        p2y = (int)rintf(fminf(fmaxf(fy2, 0.0f), (float)(SY - 1)));
        size_t i2 = base + (size_t)p2x * SY + p2y;

        d1[s - 1] = dog[i1];
        d2[s]     = dog[i2];
        if (s < 9) {
            e1 = etf[i1];
            e2 = etf[i2];
        }
    }

    float acc = 0.0f;
#pragma unroll
    for (int s = 1; s <= 9; ++s) acc = acc + (d1[s - 1] * w.g[s]);
    acc = acc + (d2[0] * w.g[0]);
#pragma unroll
    for (int s = 1; s <= 9; ++s) acc = acc + (d2[s] * w.g[s]);

    float fv = acc / w.tw;
    float th = 1.0f + fast_tanh_f32(fv);
    out[idx] = ((fv < 0.0f) && (th < 0.7f)) ? 0 : 1;
}

static double gpdf(double v, double sig) {
    return exp(-(v * v) / (2.0 * sig * sig)) / (sqrt(2.0 * M_PI) * sig);
}

extern "C" void kernel_launch(void* const* d_in, const int* in_sizes, int n_in,
                              void* d_out, int out_size, void* d_ws, size_t ws_size,
                              hipStream_t stream) {
    const float* img = (const float*)d_in[0];
    int* out = (int*)d_out;
    char* ws = (char*)d_ws;

    // Fast-path workspace layout (60 MB + 4 KB + 4 B):
    //   mag [0,4MB) (dog reuses after k_tanh) | tA [4,12) | tB [12,20)
    //   TV [20,40) | TH [40,60) | partial [60MB,+4KB) | maxbits [+4)
    const size_t need = (size_t)60 * MB + SOB_BLOCKS * sizeof(float) + 4;
    bool fast = ws_size >= need;

    float*  mag = (float*)(ws);
    float2* tA  = (float2*)(ws + (size_t)4  * MB);
    float2* tB  = (float2*)(ws + (size_t)12 * MB);
    float*  TV  = (float*)(ws + (size_t)20 * MB);
    float*  TH  = (float*)(ws + (size_t)40 * MB);
    size_t  tail = fast ? (size_t)60 * MB : (size_t)20 * MB;
    float*        partial = (float*)(ws + tail);
    unsigned int* maxbits = (unsigned int*)(ws + tail + SOB_BLOCKS * sizeof(float));

    dim3 blk(256, 1, 1);
    dim3 grd(SY / 256, SX, BN);
    dim3 vgrd(SY / VTY, SX / VTX, BN);
    dim3 hgrd(1, SX, BN);

    DogW dw;
    {
        double tw = 0.0;
        for (int t = -3; t <= 3; ++t) {
            double g = gpdf((double)t, 1.0) - 0.99 * gpdf((double)t, 1.6);
            dw.g[t + 3] = (float)g;
            tw += g;
        }
        dw.tw = (float)tw;
    }
    FdogW fw;
    {
        for (int s = 0; s <= 9; ++s) fw.g[s] = (float)gpdf((double)s, 3.0);
        double tw = 0.0;
        for (int s = 1; s <= 9; ++s) tw += gpdf((double)s, 3.0);
        for (int s = 0; s <= 9; ++s) tw += gpdf((double)s, 3.0);
        fw.tw = (float)tw;
    }

    k_sobel<<<dim3(SOB_BLOCKS, 1, 1), blk, 0, stream>>>(img, mag, tA, partial);

    float2* src = tA;
    float2* dst = tB;
    if (fast) {
        float* dogbuf = mag;   // mag is dead after k_tanh; reuse as DoG output
        k_tanh<<<grd, blk, 0, stream>>>(mag, partial, TV, TH);
        for (int it = 0; it < 3; ++it) {
            k_etf_v<<<vgrd, blk, 0, stream>>>(src, dst, TV);
            { float2* t = src; src = dst; dst = t; }
            k_etf_h<<<hgrd, blk, 0, stream>>>(src, dst, TH, img, dogbuf, dw, it == 2);
            { float2* t = src; src = dst; dst = t; }
        }
        // src holds final ETF; dogbuf holds DoG
        k_fdog<<<grd, blk, 0, stream>>>(dogbuf, src, out, fw);
    } else {
        k_reduce<<<1, 256, 0, stream>>>(partial, maxbits);
        k_norm<<<NPIX / 256, 256, 0, stream>>>(mag, maxbits);
        for (int it = 0; it < 3; ++it) {
            k_etf<<<grd, blk, 0, stream>>>(src, dst, mag, 1);
            { float2* t = src; src = dst; dst = t; }
            k_etf<<<grd, blk, 0, stream>>>(src, dst, mag, 0);
            { float2* t = src; src = dst; dst = t; }
        }
        float* dogbuf = (src == tA) ? (float*)tB : (float*)tA;
        k_dog<<<grd, blk, 0, stream>>>(img, src, dogbuf, dw);
        k_fdog<<<grd, blk, 0, stream>>>(dogbuf, src, out, fw);
    }
}